// Round 10
// baseline (219.778 us; speedup 1.0000x reference)
//
#include <hip/hip_runtime.h>
#include <cstdint>
#include <cstddef>

typedef float f32x16 __attribute__((ext_vector_type(16)));
typedef int i32x4 __attribute__((ext_vector_type(4)));
typedef int i32x8 __attribute__((ext_vector_type(8)));

#define FP8_MAX 448.0f

// async global->LDS, 16B per lane; LDS dest is wave-uniform base + lane*16
#define GL(gp, lp)                                               \
  __builtin_amdgcn_global_load_lds(                              \
      (const __attribute__((address_space(1))) void*)(gp),       \
      (__attribute__((address_space(3))) void*)(lp), 16, 0, 0)

__device__ __forceinline__ uint32_t pack4_e4m3(float a, float b, float c, float d) {
  int p = __builtin_amdgcn_cvt_pk_fp8_f32(a, b, 0, false);
  p = __builtin_amdgcn_cvt_pk_fp8_f32(c, d, p, true);
  return (uint32_t)p;
}

// Fused rowwise quant. Blocks [0,M): input rows -> row-major QA.
// Blocks [M,M+N): weight rows -> MFMA-FRAGMENT-ORDERED QWT (R7-proven):
//   k-byte k of col n -> QWT[(k>>6)*N*64 + (n>>5)*2048 + ((k>>5)&1)*1024
//                            + (n&31)*32 + (k&31)]
__global__ __launch_bounds__(256) void quant_rowwise(
    const float* __restrict__ X, const float* __restrict__ W,
    uint8_t* __restrict__ QA, uint8_t* __restrict__ QWT,
    float* __restrict__ xsc, float* __restrict__ wsc, int K, int M, int N) {
  const int row = blockIdx.x;
  const bool is_w = row >= M;
  const int r = is_w ? row - M : row;
  const float* src = (is_w ? W : X) + (size_t)r * K;
  float* rec = (is_w ? wsc : xsc) + r;

  const int tid = threadIdx.x;
  const float4* __restrict__ x4 = (const float4*)src;
  float4 v[4];
  float am = 0.0f;
#pragma unroll
  for (int i = 0; i < 4; ++i) {
    v[i] = x4[i * 256 + tid];
    am = fmaxf(am, fmaxf(fmaxf(fabsf(v[i].x), fabsf(v[i].y)),
                         fmaxf(fabsf(v[i].z), fabsf(v[i].w))));
  }
#pragma unroll
  for (int off = 32; off > 0; off >>= 1)
    am = fmaxf(am, __shfl_xor(am, off));
  __shared__ float smax[4];
  const int wave = tid >> 6, lane = tid & 63;
  if (lane == 0) smax[wave] = am;
  __syncthreads();
  am = fmaxf(fmaxf(smax[0], smax[1]), fmaxf(smax[2], smax[3]));
  am = fmaxf(am, 1e-12f);
  const float scale = FP8_MAX / am;  // exact IEEE div (no fast-math)
  if (tid == 0) rec[0] = 1.0f / scale;

#pragma unroll
  for (int i = 0; i < 4; ++i) {
    float a = fminf(fmaxf(v[i].x * scale, -FP8_MAX), FP8_MAX);
    float b = fminf(fmaxf(v[i].y * scale, -FP8_MAX), FP8_MAX);
    float c = fminf(fmaxf(v[i].z * scale, -FP8_MAX), FP8_MAX);
    float d = fminf(fmaxf(v[i].w * scale, -FP8_MAX), FP8_MAX);
    const uint32_t p = pack4_e4m3(a, b, c, d);
    if (!is_w) {
      ((uint32_t*)(QA + (size_t)r * K))[i * 256 + tid] = p;
    } else {
      ((uint32_t*)QWT)[(size_t)(i * 16 + (tid >> 4)) * (N * 16) +
                       (size_t)(r >> 5) * 512 + ((tid >> 3) & 1) * 256 +
                       (r & 31) * 8 + (tid & 7)] = p;
    }
  }
}

// ---------------------------------------------------------------------------
// MX-scaled fp8 GEMM, CONVOY-FREE schedule: MFMA(t) has zero pending-op
// dependencies. Ping-pong register frag sets (E/O): during iter t the wave
// issues {8x ds_read A-frags(t+1), 4x coalesced direct B-loads(t+1),
// 2x DMA STAGEA(t+2)} then runs the 8 MFMAs of tile t on the OTHER set
// (its waits were satisfied during iter t-1 -> compiler emits counted,
// already-retired lgkm/vmcnt).
// SAFETY vs R8 (which NaN'd):
//  - ALL vmcnt gates are vmcnt(0): counted gates are order-dependent when
//    the vmem queue mixes reorderable B-loads with global_load_lds; a full
//    drain is order-independent. (R8's prologue vmcnt(6) assumed issue
//    order the compiler doesn't guarantee -> frag reads raced the DMA.)
//  - sched_barrier(0) right after every s_barrier: s_barrier is not a
//    compiler fence, so without it ds_reads could hoist above the barrier
//    and race other waves' DMA.
// Gate retires only 1-iter-old ops (A(t+1) stages, B(t) regs) => no fresh-
// latency stall. Per-wave vmcnt(0) precedes barrier => all waves' DMA for
// slot t+1 visible before any wave reads it. Slot overwrite: frags(t-1)
// reads lgkm-retired before MFMA(t-1) (iter t-1) => barrier(top t) makes
// slot (t+2)%3==(t-1)%3 safe to DMA.
// 256x256 tile, 8 waves (2M x 4N); per-wave 128x64 = acc[4][2] f32x16.
// A frag: lane l: row=l&31, k-bytes 32*(l>>5)+0..31; LDS chunk swizzle
// stored[r][c]=logical[r][c^((r>>1)&3)] both-sides (rule #21).
// C/D 32x32: col=l&31, row=(reg&3)+8*(reg>>2)+4*(l>>5) [m74/m101].
// All E8M0 scales = 1.0 (0x7F) == exact fp8 e4m3 matmul.
// ---------------------------------------------------------------------------

#define MMS(TM, TN, A, B)                                          \
  acc[TM][TN] = __builtin_amdgcn_mfma_scale_f32_32x32x64_f8f6f4(   \
      (A), (B), acc[TM][TN], 0, 0, 0, 0x7F7F7F7F, 0, 0x7F7F7F7F);

// stage A K-tile kt (256 rows x 64 B) into abuf bi; wave w covers rows
// [w*32, w*32+32) via two GL16 (16 rows each).
#define STAGEA(KT, BI)                                                     \
  do {                                                                     \
    GL(Aq + aoff + (size_t)(KT) * 64, &lds[(BI) * 16384 + w * 2048]);      \
    GL(Aq + aoff2 + (size_t)(KT) * 64,                                     \
       &lds[(BI) * 16384 + w * 2048 + 1024]);                              \
  } while (0)

// direct coalesced B frags (tn=0,1) for K-tile TT
#define LOADB(B0, B1, TT)                                                  \
  do {                                                                     \
    const uint8_t* bp = BqT + (size_t)(TT) * nstride + bgrp;               \
    i32x4 l0 = *(const i32x4*)(bp);                                        \
    i32x4 h0 = *(const i32x4*)(bp + 16);                                   \
    i32x4 l1 = *(const i32x4*)(bp + 2048);                                 \
    i32x4 h1 = *(const i32x4*)(bp + 2064);                                 \
    B0 = __builtin_shufflevector(l0, h0, 0, 1, 2, 3, 4, 5, 6, 7);          \
    B1 = __builtin_shufflevector(l1, h1, 0, 1, 2, 3, 4, 5, 6, 7);          \
  } while (0)

__device__ __forceinline__ i32x8 ldfrag(const uint8_t* p, int off) {
  i32x4 lo = *(const i32x4*)(p + off);         // logical k-bytes 0-15
  i32x4 hi = *(const i32x4*)(p + (off ^ 16));  // logical k-bytes 16-31
  return __builtin_shufflevector(lo, hi, 0, 1, 2, 3, 4, 5, 6, 7);
}

// Consume set C (read last iter); read set N for tile T+1; MFMA tile T.
#define ITER(A0C, A1C, A2C, A3C, B0C, B1C, A0N, A1N, A2N, A3N, B0N, B1N, T) \
  do {                                                                      \
    asm volatile("s_waitcnt vmcnt(0)" ::: "memory");                        \
    __builtin_amdgcn_s_barrier();                                           \
    __builtin_amdgcn_sched_barrier(0);                                      \
    const int t1_ = ((T) + 1 < nk) ? (T) + 1 : (T);                         \
    const int pf_ = ((T) + 2 < nk) ? (T) + 2 : (T);                         \
    const int nb_ = (((T) + 1) % 3) * 16384 + arow;                         \
    A0N = ldfrag(lds, nb_);                                                 \
    A1N = ldfrag(lds, nb_ + 2048);                                          \
    A2N = ldfrag(lds, nb_ + 4096);                                          \
    A3N = ldfrag(lds, nb_ + 6144);                                          \
    LOADB(B0N, B1N, t1_);                                                   \
    STAGEA(pf_, ((T) + 2) % 3);                                             \
    __builtin_amdgcn_s_setprio(1);                                          \
    MMS(0, 0, A0C, B0C) MMS(0, 1, A0C, B1C)                                 \
    MMS(1, 0, A1C, B0C) MMS(1, 1, A1C, B1C)                                 \
    MMS(2, 0, A2C, B0C) MMS(2, 1, A2C, B1C)                                 \
    MMS(3, 0, A3C, B0C) MMS(3, 1, A3C, B1C)                                 \
    __builtin_amdgcn_s_setprio(0);                                          \
  } while (0)

__global__ __launch_bounds__(512, 1) void gemm_fp8(
    const uint8_t* __restrict__ Aq, const uint8_t* __restrict__ BqT,
    const float* __restrict__ xs, const float* __restrict__ wsc,
    const float* __restrict__ bias, float* __restrict__ C,
    int M, int N, int K) {
  __shared__ __align__(16) uint8_t lds[49152];  // 3 x 16 KiB A buffers
  const int tid = threadIdx.x;
  const int w = tid >> 6, lane = tid & 63;
  const int wrow = w >> 2, wcol = w & 3;

  // XCD-aware bijective swizzle: 512 WGs, 8 XCDs, 64 per XCD.
  int bid = (int)blockIdx.x;
  bid = (bid & 7) * 64 + (bid >> 3);
  const int bm = bid & 31, bn = bid >> 5;
  const int row0 = bm * 256, col0 = bn * 256;

  const int ln31 = lane & 31;
  const size_t nstride = (size_t)N * 64;

  // A staging source (pre-swizzled logical chunk)
  const int srow = lane >> 2;
  const int scol = 16 * ((lane & 3) ^ ((lane >> 3) & 3));
  const size_t aoff = (size_t)(row0 + w * 32 + srow) * K + scol;
  const size_t aoff2 = aoff + (size_t)16 * K;

  // A ds_read base: row = wrow*128 + ln31 (+tm*32), chunk = logical^((r>>1)&3)
  const int g2 = (lane >> 5) * 2;
  const int o0 = 16 * (g2 ^ ((ln31 >> 1) & 3));
  const int arow = (wrow * 128 + ln31) * 64 + o0;

  // B direct-load base (fragment-ordered): wave's col-group, lane's 32 B
  const size_t bgrp = (size_t)((col0 + wcol * 64) >> 5) * 2048 + (size_t)lane * 32;

  f32x16 zero = {};
  f32x16 acc[4][2];
#pragma unroll
  for (int m = 0; m < 4; ++m)
#pragma unroll
    for (int n = 0; n < 2; ++n) acc[m][n] = zero;

  const int nk = K / 64;
  i32x8 aE0, aE1, aE2, aE3, bE0, bE1;
  i32x8 aO0, aO1, aO2, aO3, bO0, bO1;

  // prologue: A(0)->slot0, A(1)->slot1, B(0)->E; FULL drain (order-
  // independent, unlike a counted gate on a mixed/reorderable vmem queue),
  // then barrier, then read A-frags(0)->E.
  STAGEA(0, 0);
  STAGEA(1, 1);
  LOADB(bE0, bE1, 0);
  asm volatile("s_waitcnt vmcnt(0)" ::: "memory");
  __builtin_amdgcn_s_barrier();
  __builtin_amdgcn_sched_barrier(0);
  aE0 = ldfrag(lds, arow);
  aE1 = ldfrag(lds, arow + 2048);
  aE2 = ldfrag(lds, arow + 4096);
  aE3 = ldfrag(lds, arow + 6144);

  for (int t = 0; t < nk; t += 2) {
    ITER(aE0, aE1, aE2, aE3, bE0, bE1, aO0, aO1, aO2, aO3, bO0, bO1, t);
    ITER(aO0, aO1, aO2, aO3, bO0, bO1, aE0, aE1, aE2, aE3, bE0, bE1, t + 1);
  }

  // epilogue: C/D 32x32 layout col=lane&31, row=(reg&3)+8*(reg>>2)+4*(lane>>5)
  const int cl = lane & 31;
  const int rtop = (lane >> 5) * 4;
#pragma unroll
  for (int tm = 0; tm < 4; ++tm) {
#pragma unroll
    for (int tn = 0; tn < 2; ++tn) {
      const int col = col0 + wcol * 64 + tn * 32 + cl;
      const float wsn = wsc[col];
      const float bb = bias[col];
      const int rowb = row0 + wrow * 128 + tm * 32 + rtop;
#pragma unroll
      for (int q = 0; q < 4; ++q) {
        const float4 xq = *(const float4*)&xs[rowb + 8 * q];
        const float xa[4] = {xq.x, xq.y, xq.z, xq.w};
#pragma unroll
        for (int j = 0; j < 4; ++j) {
          const int r = rowb + 8 * q + j;
          C[(size_t)r * N + col] = fmaf(acc[tm][tn][4 * q + j] * xa[j], wsn, bb);
        }
      }
    }
  }
}

extern "C" void kernel_launch(void* const* d_in, const int* in_sizes, int n_in,
                              void* d_out, int out_size, void* d_ws, size_t ws_size,
                              hipStream_t stream) {
  const float* input = (const float*)d_in[0];   // [M,K] fp32
  const float* weight = (const float*)d_in[1];  // [N,K] fp32
  const float* bias = (const float*)d_in[2];    // [N]   fp32
  float* out = (float*)d_out;                   // [M,N] fp32

  const int K = 4096;
  const int N = in_sizes[2];
  const int M = in_sizes[0] / K;

  uint8_t* qA = (uint8_t*)d_ws;                    // [M,K] row-major
  uint8_t* qWT = qA + (size_t)M * K;               // fragment-ordered
  float* xsc = (float*)(qWT + (size_t)N * K);
  float* wsc = xsc + M;

  quant_rowwise<<<M + N, 256, 0, stream>>>(input, weight, qA, qWT, xsc, wsc,
                                           K, M, N);

  dim3 grid((M / 256) * (N / 256));
  gemm_fp8<<<grid, 512, 0, stream>>>(qA, qWT, xsc, wsc, bias, out, M, N, K);
}

// Round 11
// 195.619 us; speedup vs baseline: 1.1235x; 1.1235x over previous
//
#include <hip/hip_runtime.h>
#include <cstdint>
#include <cstddef>

typedef float f32x16 __attribute__((ext_vector_type(16)));
typedef int i32x4 __attribute__((ext_vector_type(4)));
typedef int i32x8 __attribute__((ext_vector_type(8)));

#define FP8_MAX 448.0f

// async global->LDS, 16B per lane; LDS dest is wave-uniform base + lane*16
#define GL(gp, lp)                                               \
  __builtin_amdgcn_global_load_lds(                              \
      (const __attribute__((address_space(1))) void*)(gp),       \
      (__attribute__((address_space(3))) void*)(lp), 16, 0, 0)

__device__ __forceinline__ uint32_t pack4_e4m3(float a, float b, float c, float d) {
  int p = __builtin_amdgcn_cvt_pk_fp8_f32(a, b, 0, false);
  p = __builtin_amdgcn_cvt_pk_fp8_f32(c, d, p, true);
  return (uint32_t)p;
}

// Fused rowwise quant: blocks [0,M) -> QA rows, [M,M+N) -> QW rows (both
// row-major; B returns to LDS staging this round).
__global__ __launch_bounds__(256) void quant_rowwise(
    const float* __restrict__ X, const float* __restrict__ W,
    uint8_t* __restrict__ QA, uint8_t* __restrict__ QW,
    float* __restrict__ xsc, float* __restrict__ wsc, int K, int M) {
  const int row = blockIdx.x;
  const bool is_w = row >= M;
  const int r = is_w ? row - M : row;
  const float* src = (is_w ? W : X) + (size_t)r * K;
  uint8_t* q = (is_w ? QW : QA) + (size_t)r * K;
  float* rec = (is_w ? wsc : xsc) + r;

  const int tid = threadIdx.x;
  const float4* __restrict__ x4 = (const float4*)src;
  float4 v[4];
  float am = 0.0f;
#pragma unroll
  for (int i = 0; i < 4; ++i) {
    v[i] = x4[i * 256 + tid];
    am = fmaxf(am, fmaxf(fmaxf(fabsf(v[i].x), fabsf(v[i].y)),
                         fmaxf(fabsf(v[i].z), fabsf(v[i].w))));
  }
#pragma unroll
  for (int off = 32; off > 0; off >>= 1)
    am = fmaxf(am, __shfl_xor(am, off));
  __shared__ float smax[4];
  const int wave = tid >> 6, lane = tid & 63;
  if (lane == 0) smax[wave] = am;
  __syncthreads();
  am = fmaxf(fmaxf(smax[0], smax[1]), fmaxf(smax[2], smax[3]));
  am = fmaxf(am, 1e-12f);
  const float scale = FP8_MAX / am;  // exact IEEE div (no fast-math)
  if (tid == 0) rec[0] = 1.0f / scale;
  uint32_t* __restrict__ q32 = (uint32_t*)q;
#pragma unroll
  for (int i = 0; i < 4; ++i) {
    float a = fminf(fmaxf(v[i].x * scale, -FP8_MAX), FP8_MAX);
    float b = fminf(fmaxf(v[i].y * scale, -FP8_MAX), FP8_MAX);
    float c = fminf(fmaxf(v[i].z * scale, -FP8_MAX), FP8_MAX);
    float d = fminf(fmaxf(v[i].w * scale, -FP8_MAX), FP8_MAX);
    q32[i * 256 + tid] = pack4_e4m3(a, b, c, d);
  }
}

// ---------------------------------------------------------------------------
// MX-scaled fp8 GEMM (all E8M0 scales = 1.0 == exact fp8 e4m3 matmul) in the
// m201 8-phase-style template at MX geometry: 4 phases per K-tile, each
//   { ds_read this phase's frags ; issue 1 stage pair ; barrier ;
//     lgkmcnt(0) ; setprio(1) ; 2x MFMA ; setprio(0) ; barrier }
// Reads are compiler-visible loads -> MFMA/read ordering is dataflow-
// enforced (m201 pattern, no sched_barriers).
// A and B both LDS triple-buffered (3 x 16 KiB each = 96 KiB), distance-2
// DMA prefetch, PURE global_load_lds vmem queue -> counted gate is order-
// safe (R5 hardware-proven): vmcnt(4) ONCE per K-tile at P3.
// Ledger (4 GL/iter: B(t+2)x2 @P0, A(t+2)x2 @P1): at P3 of t the queue is
// [B(t+1)x2, A(t+1)x2, B(t+2)x2, A(t+2)x2]; vmcnt(4) retires t+1's four
// (needed next iter), leaves t+2's in flight. Slack >= 1 full iter.
// Prologue issues tile-0's 4 GLs before tile-1's -> vmcnt(4) confirms
// tile 0 and leaves tile 1 pending.
// 256x256 tile, 8 waves (2M x 4N); per-wave 128x64 = acc[4][2] f32x16.
// Frags: lane l holds row/col=l&31, k-bytes 32*(l>>5)+0..31; LDS chunk
// swizzle stored[r][c]=logical[r][c^((r>>1)&3)] both-sides (rule #21).
// C/D 32x32: col=l&31, row=(reg&3)+8*(reg>>2)+4*(l>>5) [m74/m101].
// ---------------------------------------------------------------------------

#define MMS(TM, TN, A, B)                                          \
  acc[TM][TN] = __builtin_amdgcn_mfma_scale_f32_32x32x64_f8f6f4(   \
      (A), (B), acc[TM][TN], 0, 0, 0, 0x7F7F7F7F, 0, 0x7F7F7F7F);

// stage 32 rows of A K-tile kt into A-slot BI (2 GL, 16 rows each)
#define STAGEA(KT, BI)                                                     \
  do {                                                                     \
    GL(Aq + aoff + (size_t)(KT) * 64, &lds[(BI) * 16384 + w * 2048]);      \
    GL(Aq + aoff2 + (size_t)(KT) * 64,                                     \
       &lds[(BI) * 16384 + w * 2048 + 1024]);                              \
  } while (0)

// stage 32 cols of B K-tile kt into B-slot BI (2 GL)
#define STAGEB(KT, BI)                                                     \
  do {                                                                     \
    GL(Bq + boff + (size_t)(KT) * 64,                                      \
       &lds[49152 + (BI) * 16384 + w * 2048]);                             \
    GL(Bq + boff2 + (size_t)(KT) * 64,                                     \
       &lds[49152 + (BI) * 16384 + w * 2048 + 1024]);                      \
  } while (0)

__device__ __forceinline__ i32x8 ldfrag(const uint8_t* p, int off) {
  i32x4 lo = *(const i32x4*)(p + off);         // logical k-bytes 0-15
  i32x4 hi = *(const i32x4*)(p + (off ^ 16));  // logical k-bytes 16-31
  return __builtin_shufflevector(lo, hi, 0, 1, 2, 3, 4, 5, 6, 7);
}

__global__ __launch_bounds__(512, 1) void gemm_fp8(
    const uint8_t* __restrict__ Aq, const uint8_t* __restrict__ Bq,
    const float* __restrict__ xs, const float* __restrict__ wsc,
    const float* __restrict__ bias, float* __restrict__ C,
    int M, int N, int K) {
  __shared__ __align__(16) uint8_t lds[98304];  // A: 3x16K @0, B: 3x16K @49152
  const int tid = threadIdx.x;
  const int w = tid >> 6, lane = tid & 63;
  const int wrow = w >> 2, wcol = w & 3;

  // XCD-aware bijective swizzle: 512 WGs, 8 XCDs, 64 per XCD.
  int bid = (int)blockIdx.x;
  bid = (bid & 7) * 64 + (bid >> 3);
  const int bm = bid & 31, bn = bid >> 5;
  const int row0 = bm * 256, col0 = bn * 256;

  const int ln31 = lane & 31;

  // staging source offsets (pre-swizzled logical chunk)
  const int srow = lane >> 2;
  const int scol = 16 * ((lane & 3) ^ ((lane >> 3) & 3));
  const size_t aoff = (size_t)(row0 + w * 32 + srow) * K + scol;
  const size_t aoff2 = aoff + (size_t)16 * K;
  const size_t boff = (size_t)(col0 + w * 32 + srow) * K + scol;
  const size_t boff2 = boff + (size_t)16 * K;

  // ds_read bases: row r = base+(lane&31); first logical chunk 2*(lane>>5);
  // stored chunk = logical ^ ((r>>1)&3)
  const int g2 = (lane >> 5) * 2;
  const int o0 = 16 * (g2 ^ ((ln31 >> 1) & 3));
  const int arow = (wrow * 128 + ln31) * 64 + o0;  // + tm*2048
  const int brow = (wcol * 64 + ln31) * 64 + o0;   // + tn*2048

  f32x16 zero = {};
  f32x16 acc[4][2];
#pragma unroll
  for (int m = 0; m < 4; ++m)
#pragma unroll
    for (int n = 0; n < 2; ++n) acc[m][n] = zero;

  const int nk = K / 64;

  // prologue: tile 0 then tile 1 (order matters for the counted gate);
  // vmcnt(4) retires tile 0's four, leaves tile 1's in flight.
  STAGEA(0, 0); STAGEB(0, 0);
  STAGEA(1, 1); STAGEB(1, 1);
  asm volatile("s_waitcnt vmcnt(4)" ::: "memory");
  __builtin_amdgcn_s_barrier();

  for (int t = 0; t < nk; ++t) {
    const int sA = (t % 3) * 16384;
    const int sB = 49152 + (t % 3) * 16384;
    const int pb = (t + 2) % 3;
    const int pf = (t + 2 < nk) ? t + 2 : t;  // clamped tail prefetch (dead)

    // ---- P0: frags b0,b1,a0 ; stage B(t+2)
    i32x8 b0 = ldfrag(lds, sB + brow);
    i32x8 b1 = ldfrag(lds, sB + brow + 2048);
    i32x8 a0 = ldfrag(lds, sA + arow);
    STAGEB(pf, pb);
    __builtin_amdgcn_s_barrier();
    asm volatile("s_waitcnt lgkmcnt(0)" ::: "memory");
    __builtin_amdgcn_s_setprio(1);
    MMS(0, 0, a0, b0) MMS(0, 1, a0, b1)
    __builtin_amdgcn_s_setprio(0);
    __builtin_amdgcn_s_barrier();

    // ---- P1: frag a1 ; stage A(t+2)
    i32x8 a1 = ldfrag(lds, sA + arow + 2048);
    STAGEA(pf, pb);
    __builtin_amdgcn_s_barrier();
    asm volatile("s_waitcnt lgkmcnt(0)" ::: "memory");
    __builtin_amdgcn_s_setprio(1);
    MMS(1, 0, a1, b0) MMS(1, 1, a1, b1)
    __builtin_amdgcn_s_setprio(0);
    __builtin_amdgcn_s_barrier();

    // ---- P2: frag a2
    i32x8 a2 = ldfrag(lds, sA + arow + 4096);
    __builtin_amdgcn_s_barrier();
    asm volatile("s_waitcnt lgkmcnt(0)" ::: "memory");
    __builtin_amdgcn_s_setprio(1);
    MMS(2, 0, a2, b0) MMS(2, 1, a2, b1)
    __builtin_amdgcn_s_setprio(0);
    __builtin_amdgcn_s_barrier();

    // ---- P3: frag a3 ; K-tile gate (counted, never drains)
    i32x8 a3 = ldfrag(lds, sA + arow + 6144);
    asm volatile("s_waitcnt vmcnt(4)" ::: "memory");
    __builtin_amdgcn_s_barrier();
    asm volatile("s_waitcnt lgkmcnt(0)" ::: "memory");
    __builtin_amdgcn_s_setprio(1);
    MMS(3, 0, a3, b0) MMS(3, 1, a3, b1)
    __builtin_amdgcn_s_setprio(0);
    __builtin_amdgcn_s_barrier();
  }

  // epilogue: C/D 32x32 layout col=lane&31, row=(reg&3)+8*(reg>>2)+4*(lane>>5)
  const int cl = lane & 31;
  const int rtop = (lane >> 5) * 4;
#pragma unroll
  for (int tm = 0; tm < 4; ++tm) {
#pragma unroll
    for (int tn = 0; tn < 2; ++tn) {
      const int col = col0 + wcol * 64 + tn * 32 + cl;
      const float wsn = wsc[col];
      const float bb = bias[col];
      const int rowb = row0 + wrow * 128 + tm * 32 + rtop;
#pragma unroll
      for (int q = 0; q < 4; ++q) {
        const float4 xq = *(const float4*)&xs[rowb + 8 * q];
        const float xa[4] = {xq.x, xq.y, xq.z, xq.w};
#pragma unroll
        for (int j = 0; j < 4; ++j) {
          const int r = rowb + 8 * q + j;
          C[(size_t)r * N + col] = fmaf(acc[tm][tn][4 * q + j] * xa[j], wsn, bb);
        }
      }
    }
  }
}

extern "C" void kernel_launch(void* const* d_in, const int* in_sizes, int n_in,
                              void* d_out, int out_size, void* d_ws, size_t ws_size,
                              hipStream_t stream) {
  const float* input = (const float*)d_in[0];   // [M,K] fp32
  const float* weight = (const float*)d_in[1];  // [N,K] fp32
  const float* bias = (const float*)d_in[2];    // [N]   fp32
  float* out = (float*)d_out;                   // [M,N] fp32

  const int K = 4096;
  const int N = in_sizes[2];
  const int M = in_sizes[0] / K;

  uint8_t* qA = (uint8_t*)d_ws;                    // [M,K] row-major
  uint8_t* qW = qA + (size_t)M * K;                // [N,K] row-major
  float* xsc = (float*)(qW + (size_t)N * K);
  float* wsc = xsc + M;

  quant_rowwise<<<M + N, 256, 0, stream>>>(input, weight, qA, qW, xsc, wsc, K, M);

  dim3 grid((M / 256) * (N / 256));
  gemm_fp8<<<grid, 512, 0, stream>>>(qA, qW, xsc, wsc, bias, out, M, N, K);
}